// Round 1
// baseline (1623.049 us; speedup 1.0000x reference)
//
#include <hip/hip_runtime.h>
#include <hip/hip_bf16.h>

// Fused flash-style softmax(Q V^T) V for B=4, NQ=NK=4096, D=1024 (fp32 in/out).
// - Block = 32 q-rows x full NK loop; 8 waves, wave w owns d-slice [128w, 128w+128).
// - QK^T computed swapped (S^T = mfma(V, Q)) so both operands are d-contiguous.
//   hi/lo bf16 split, 3-product MFMA for near-fp32 scores.
// - Cross-wave D-reduction of S^T partials through LDS; online softmax; PV in bf16
//   from a swizzled wave-private Vhi LDS tile.

#define NB   4
#define NQL  4096
#define NKL  4096
#define DIM  1024
#define BQ   32
#define BK   32
#define NW   8
#define DSL  128
#define NTILES (NKL / BK)

typedef float f32x4 __attribute__((ext_vector_type(4)));
typedef short bf16x8 __attribute__((ext_vector_type(8)));

__device__ __forceinline__ short f2bf(float x) {
    return __builtin_bit_cast(short, __float2bfloat16(x));
}
__device__ __forceinline__ float bf2f(short s) {
    return __builtin_bit_cast(float, ((unsigned)(unsigned short)s) << 16);
}

// Vhi LDS addressing: wave-private [BK][DSL] bf16 tile, slot-swizzled so that
// b128 stage-writes are bank-optimal and u16 PV reads are conflict-free.
__device__ __forceinline__ int vhi_off(int k, int dloc) {  // byte offset in wave region
    int slot = ((k & 7) + 2 * ((k >> 3) & 3)) & 7;
    return k * (DSL * 2) + ((dloc * 2) ^ (slot * 16));
}

// S-partial buffer index permutation: bank-friendly for both the MFMA-layout
// writes (offsets {0,8,16,24} across lane groups -> 2-way max) and softmax reads.
__device__ __forceinline__ int sp_idx(int q, int k) {
    int kp = (k & 3) | (((k >> 4) & 1) << 2) | (((k >> 3) & 1) << 3) | (((k >> 2) & 1) << 4);
    return (q + kp) & 31;
}

__global__ __launch_bounds__(512, 2)
void attn_fused(const float* __restrict__ Qg, const float* __restrict__ Vg,
                float* __restrict__ Og) {
    __shared__ __align__(16) short vhi_s[NW * BK * DSL];  // 64 KB
    __shared__ float spart[NW][BQ][BK];                   // 32 KB
    __shared__ __align__(16) short pbuf[BQ * BK];         // 2 KB
    __shared__ float mrun[BQ], lrun[BQ], arun[BQ];

    const int tid = (int)threadIdx.x;
    const int l   = tid & 63;
    const int w   = tid >> 6;
    const int l15 = l & 15;
    const int lg  = l >> 4;

    const int b  = (int)blockIdx.x >> 7;
    const int qt = (int)blockIdx.x & 127;
    const int q0 = qt * BQ;
    const int dw = w * DSL;

    if (tid < BQ) { mrun[tid] = -3e38f; lrun[tid] = 0.f; arun[tid] = 1.f; }

    // Q fragments (B-operand layout: lane holds Q[q0+qb*16+l15][8 consecutive d]),
    // hi/lo bf16 split. 64 VGPRs total, resident for the whole kernel.
    bf16x8 qhi[2][4], qlo[2][4];
#pragma unroll
    for (int qb = 0; qb < 2; ++qb) {
#pragma unroll
        for (int dc = 0; dc < 4; ++dc) {
            const float* qp = Qg + (size_t)(b * NQL + q0 + qb * 16 + l15) * DIM
                            + dw + dc * 32 + lg * 8;
            f32x4 x0 = *(const f32x4*)qp;
            f32x4 x1 = *(const f32x4*)(qp + 4);
#pragma unroll
            for (int j = 0; j < 8; ++j) {
                float x = (j < 4) ? x0[j] : x1[j - 4];
                short h = f2bf(x);
                qhi[qb][dc][j] = h;
                qlo[qb][dc][j] = f2bf(x - bf2f(h));
            }
        }
    }

    f32x4 oacc[2][8];
#pragma unroll
    for (int qb = 0; qb < 2; ++qb)
#pragma unroll
        for (int dg = 0; dg < 8; ++dg)
            oacc[qb][dg] = (f32x4){0.f, 0.f, 0.f, 0.f};

    short* vbase = vhi_s + w * (BK * DSL);

    // softmax assignment: this lane handles q = 4w+lg, k = l15 and l15+16
    const int qsm = 4 * w + lg;
    const int rk0 = sp_idx(qsm, l15);
    const int rk1 = sp_idx(qsm, l15 + 16);

    __syncthreads();

    for (int kt = 0; kt < NTILES; ++kt) {
        const int kbase = kt * BK;
        f32x4 sacc[2][2];
#pragma unroll
        for (int kb = 0; kb < 2; ++kb)
#pragma unroll
            for (int qb = 0; qb < 2; ++qb)
                sacc[kb][qb] = (f32x4){0.f, 0.f, 0.f, 0.f};

        // Phase 1: load V slice (fp32), split hi/lo, stage Vhi to LDS, QK^T MFMAs
#pragma unroll
        for (int dc = 0; dc < 4; ++dc) {
            bf16x8 vhi[2], vlo[2];
#pragma unroll
            for (int kb = 0; kb < 2; ++kb) {
                const int kvl = kb * 16 + l15;
                const float* vp = Vg + (size_t)(b * NKL + kbase + kvl) * DIM
                                + dw + dc * 32 + lg * 8;
                f32x4 x0 = *(const f32x4*)vp;
                f32x4 x1 = *(const f32x4*)(vp + 4);
#pragma unroll
                for (int j = 0; j < 8; ++j) {
                    float x = (j < 4) ? x0[j] : x1[j - 4];
                    short h = f2bf(x);
                    vhi[kb][j] = h;
                    vlo[kb][j] = f2bf(x - bf2f(h));
                }
                *(bf16x8*)((char*)vbase + vhi_off(kvl, dc * 32 + lg * 8)) = vhi[kb];
            }
#pragma unroll
            for (int kb = 0; kb < 2; ++kb)
#pragma unroll
                for (int qb = 0; qb < 2; ++qb) {
                    sacc[kb][qb] = __builtin_amdgcn_mfma_f32_16x16x32_bf16(
                        vhi[kb], qhi[qb][dc], sacc[kb][qb], 0, 0, 0);
                    sacc[kb][qb] = __builtin_amdgcn_mfma_f32_16x16x32_bf16(
                        vhi[kb], qlo[qb][dc], sacc[kb][qb], 0, 0, 0);
                    sacc[kb][qb] = __builtin_amdgcn_mfma_f32_16x16x32_bf16(
                        vlo[kb], qhi[qb][dc], sacc[kb][qb], 0, 0, 0);
                }
        }

        // Write S^T partials (acc layout: row k = kb*16+4*lg+r, col q = qb*16+l15)
#pragma unroll
        for (int kb = 0; kb < 2; ++kb)
#pragma unroll
            for (int qb = 0; qb < 2; ++qb)
#pragma unroll
                for (int r = 0; r < 4; ++r) {
                    int k = kb * 16 + lg * 4 + r;
                    int q = qb * 16 + l15;
                    spart[w][q][sp_idx(q, k)] = sacc[kb][qb][r];
                }
        __syncthreads();  // B1: all partials visible

        // Phase 2: reduce partials over waves, online softmax for q = qsm
        {
            float s0 = 0.f, s1 = 0.f;
#pragma unroll
            for (int wv = 0; wv < NW; ++wv) {
                s0 += spart[wv][qsm][rk0];
                s1 += spart[wv][qsm][rk1];
            }
            float mloc = fmaxf(s0, s1);
#pragma unroll
            for (int off = 1; off < 16; off <<= 1)
                mloc = fmaxf(mloc, __shfl_xor(mloc, off));
            float mold = mrun[qsm];
            float mnew = fmaxf(mold, mloc);
            float p0 = __expf(s0 - mnew);
            float p1 = __expf(s1 - mnew);
            float rs = p0 + p1;
#pragma unroll
            for (int off = 1; off < 16; off <<= 1)
                rs += __shfl_xor(rs, off);
            float alpha = __expf(mold - mnew);
            if (l15 == 0) {
                mrun[qsm] = mnew;
                lrun[qsm] = alpha * lrun[qsm] + rs;
                arun[qsm] = alpha;
            }
            pbuf[qsm * BK + l15]      = f2bf(p0);
            pbuf[qsm * BK + l15 + 16] = f2bf(p1);
        }
        __syncthreads();  // B2: P/alpha/m/l visible; guards S-partial reuse

        // Phase 3: rescale O by alpha, then O += P * Vhi
        float av[2][4];
#pragma unroll
        for (int qb = 0; qb < 2; ++qb)
#pragma unroll
            for (int r = 0; r < 4; ++r)
                av[qb][r] = arun[qb * 16 + lg * 4 + r];
#pragma unroll
        for (int qb = 0; qb < 2; ++qb)
#pragma unroll
            for (int dg = 0; dg < 8; ++dg)
#pragma unroll
                for (int r = 0; r < 4; ++r)
                    oacc[qb][dg][r] *= av[qb][r];

        bf16x8 pfrag[2];
#pragma unroll
        for (int qb = 0; qb < 2; ++qb)
            pfrag[qb] = *(const bf16x8*)(pbuf + (qb * 16 + l15) * BK + lg * 8);

#pragma unroll
        for (int dg = 0; dg < 8; ++dg) {
            bf16x8 bfrag;
#pragma unroll
            for (int j = 0; j < 8; ++j) {
                int k = lg * 8 + j;
                bfrag[j] = *(const short*)((const char*)vbase + vhi_off(k, dg * 16 + l15));
            }
#pragma unroll
            for (int qb = 0; qb < 2; ++qb)
                oacc[qb][dg] = __builtin_amdgcn_mfma_f32_16x16x32_bf16(
                    pfrag[qb], bfrag, oacc[qb][dg], 0, 0, 0);
        }
    }

    // Epilogue: divide by softmax denominator, store fp32
#pragma unroll
    for (int qb = 0; qb < 2; ++qb) {
        float il[4];
#pragma unroll
        for (int r = 0; r < 4; ++r)
            il[r] = 1.0f / lrun[qb * 16 + lg * 4 + r];
#pragma unroll
        for (int dg = 0; dg < 8; ++dg)
#pragma unroll
            for (int r = 0; r < 4; ++r) {
                int q = q0 + qb * 16 + lg * 4 + r;
                int d = dw + dg * 16 + l15;
                Og[(size_t)(b * NQL + q) * DIM + d] = oacc[qb][dg][r] * il[r];
            }
    }
}

extern "C" void kernel_launch(void* const* d_in, const int* in_sizes, int n_in,
                              void* d_out, int out_size, void* d_ws, size_t ws_size,
                              hipStream_t stream) {
    const float* Q = (const float*)d_in[0];
    const float* V = (const float*)d_in[1];
    float* O = (float*)d_out;
    (void)in_sizes; (void)n_in; (void)out_size; (void)d_ws; (void)ws_size;
    dim3 grid(NB * (NQL / BQ));  // 512 blocks
    dim3 block(NW * 64);         // 512 threads
    attn_fused<<<grid, block, 0, stream>>>(Q, V, O);
}